// Round 10
// baseline (123.268 us; speedup 1.0000x reference)
//
#include <hip/hip_runtime.h>

#define G 16
#define T 4096
#define DD 64

typedef __attribute__((ext_vector_type(8))) short bf16x8;
typedef __attribute__((ext_vector_type(4))) short bf16x4;
typedef __attribute__((ext_vector_type(4))) float f32x4;
typedef unsigned short U16;

__device__ __forceinline__ float bf2f(U16 u) {
  union { unsigned int u; float f; } x; x.u = ((unsigned int)u) << 16; return x.f;
}
__device__ __forceinline__ U16 f2bf(float f) {
  union { float f; unsigned int u; } x; x.f = f;
  unsigned int r = x.u + 0x7FFFu + ((x.u >> 16) & 1u);
  return (U16)(r >> 16);
}

#define MFMA(a, b, c) __builtin_amdgcn_mfma_f32_16x16x32_bf16((a), (b), (c), 0, 0, 0)

// ln(10000)/32
#define ROPE_C 0.28782313662425575f

// ---------------- Kernel A: rope K -> Kr + KrT; V -> VT + VbT; X^T = Kr^T V -> Xu;
//                  last block per head: agent-acquire + in-place exclusive block-prefix ----------------
__global__ __launch_bounds__(256) void k_phaseA(const float* __restrict__ K, const float* __restrict__ V,
                                                U16* __restrict__ Kr, U16* __restrict__ VbT,
                                                U16* __restrict__ Xu, unsigned* __restrict__ cnt) {
  __shared__ __align__(16) U16 KrT[64][72];   // [d][k]
  __shared__ __align__(16) U16 VT[64][72];    // [e][k]
  __shared__ unsigned lastFlag;
  int wid = blockIdx.x;            // g*64 + b
  int g = wid >> 6, b = wid & 63;
  int k0 = b * 64;
  int tid = threadIdx.x;

  int r = tid >> 2, qq = tid & 3, d0 = qq * 8;
  int t = k0 + r;
  size_t base = ((size_t)g * T + t) * DD;

  // K path: rope (inline trig) -> Kr global + KrT LDS (transposed scatter)
  {
    const float* rp = K + base;
    float x1[8], x2[8];
    *(float4*)&x1[0] = *(const float4*)(rp + d0);
    *(float4*)&x1[4] = *(const float4*)(rp + d0 + 4);
    *(float4*)&x2[0] = *(const float4*)(rp + d0 + 32);
    *(float4*)&x2[4] = *(const float4*)(rp + d0 + 36);
    bf16x8 v1, v2;
#pragma unroll
    for (int i = 0; i < 8; ++i) {
      float invf = __expf(-(float)(d0 + i) * ROPE_C);
      float ang = (float)t * invf;
      float s, c;
      __sincosf(ang, &s, &c);
      float o1 = x1[i] * c - x2[i] * s;
      float o2 = x1[i] * s + x2[i] * c;
      U16 b1 = f2bf(o1), b2 = f2bf(o2);
      v1[i] = (short)b1; v2[i] = (short)b2;
      KrT[d0 + i][r]      = b1;
      KrT[d0 + i + 32][r] = b2;
    }
    *(bf16x8*)(Kr + base + d0)      = v1;
    *(bf16x8*)(Kr + base + d0 + 32) = v2;
  }
  // V path: f32 -> bf16 -> VT LDS (transposed scatter)
  {
    const float* vp = V + base;
    float y1[8], y2[8];
    *(float4*)&y1[0] = *(const float4*)(vp + d0);
    *(float4*)&y1[4] = *(const float4*)(vp + d0 + 4);
    *(float4*)&y2[0] = *(const float4*)(vp + d0 + 32);
    *(float4*)&y2[4] = *(const float4*)(vp + d0 + 36);
#pragma unroll
    for (int i = 0; i < 8; ++i) {
      VT[d0 + i][r]      = f2bf(y1[i]);
      VT[d0 + i + 32][r] = f2bf(y2[i]);
    }
  }
  __syncthreads();

  // export V^T to global (vector LDS read -> dwordx4 stores)
  {
    int er = tid >> 2, cc = (tid & 3) * 16;
    *(bf16x8*)(VbT + ((size_t)wid << 12) + er * 64 + cc)     = *(const bf16x8*)&VT[er][cc];
    *(bf16x8*)(VbT + ((size_t)wid << 12) + er * 64 + cc + 8) = *(const bf16x8*)&VT[er][cc + 8];
  }

  int lane = tid & 63, wv = tid >> 6;
  int lr = lane & 15, lg = lane >> 4;

  // X^T = Kr^T * V (role-swapped layout, verified in R8); plain b64 stores
  {
    bf16x8 A0 = *(const bf16x8*)&KrT[16 * wv + lr][8 * lg];
    bf16x8 A1 = *(const bf16x8*)&KrT[16 * wv + lr][8 * lg + 32];
#pragma unroll
    for (int et = 0; et < 4; ++et) {
      bf16x8 B0 = *(const bf16x8*)&VT[16 * et + lr][8 * lg];
      bf16x8 B1 = *(const bf16x8*)&VT[16 * et + lr][8 * lg + 32];
      f32x4 acc = {0.f, 0.f, 0.f, 0.f};
      acc = MFMA(A0, B0, acc);
      acc = MFMA(A1, B1, acc);
      bf16x4 st;
#pragma unroll
      for (int rr = 0; rr < 4; ++rr) st[rr] = (short)f2bf(acc[rr]);
      *(bf16x4*)(Xu + ((size_t)wid << 12) + (16 * et + lr) * 64 + 16 * wv + 4 * lg) = st;
    }
  }

  // ---- completion gate with agent-scope release/acquire (fixes R9's race) ----
  __syncthreads();   // compiler drains vmcnt(0) per wave before s_barrier -> all stores in L2
  if (tid == 0) {
    // release: buffer_wbl2 + wait -> this block's dirty lines reach the L3 coherence point
    __builtin_amdgcn_fence(__ATOMIC_RELEASE, "agent");
    // atomicInc wrap-at-63: the 64th incrementer per head per launch sees old==62,
    // for ANY initial value >= 63 (0xAA poison or steady-state 63). No reset pass needed.
    unsigned old = atomicInc(&cnt[g], 63u);
    lastFlag = (old == 62u) ? 1u : 0u;
  }
  __syncthreads();

  if (lastFlag) {
    // acquire: buffer_inv -> drop possibly-stale clean L2 lines before reading other XCDs' data
    __builtin_amdgcn_fence(__ATOMIC_ACQUIRE, "agent");
    // exclusive prefix over the 64 block matrices of head g; 16 contiguous cols/thread;
    // 2-deep pipelined (load row bb+1 while processing row bb)
    int c0 = tid * 16;
    U16* hx = Xu + ((size_t)g << 18) + c0;
    float acc[16];
#pragma unroll
    for (int j = 0; j < 16; ++j) acc[j] = 0.f;
    bf16x8 lo = *(const bf16x8*)hx;
    bf16x8 hi = *(const bf16x8*)(hx + 8);
    for (int bb = 0; bb < 64; ++bb) {
      U16* rowp = hx + ((size_t)bb << 12);
      bf16x8 nlo, nhi;
      if (bb < 63) {
        nlo = *(const bf16x8*)(rowp + 4096);
        nhi = *(const bf16x8*)(rowp + 4096 + 8);
      }
      bf16x8 olo, ohi;
#pragma unroll
      for (int j = 0; j < 8; ++j) {
        olo[j] = (short)f2bf(acc[j]);
        ohi[j] = (short)f2bf(acc[j + 8]);
        acc[j]     += bf2f((U16)lo[j]);
        acc[j + 8] += bf2f((U16)hi[j]);
      }
      *(bf16x8*)rowp       = olo;
      *(bf16x8*)(rowp + 8) = ohi;
      lo = nlo; hi = nhi;
    }
  }
}

// ---------------- Kernel B: O_b = rope(Q)_b * Sp_b + tril_strict(rope(Q)_b Kr_b^T) V_b ----------------
__global__ __launch_bounds__(256) void k_phase3(const float* __restrict__ Q, const U16* __restrict__ Kr,
                                                const U16* __restrict__ VbT, const U16* __restrict__ Xu,
                                                float* __restrict__ Out) {
  __shared__ __align__(16) U16 SP[64][72];     // Sp^T [e][d]
  __shared__ __align__(16) U16 VT[64][72];     // [e][k]
  __shared__ __align__(16) U16 SW[4][16][72];  // per-wave masked S round-trip
  int wid = blockIdx.x;
  int g = wid >> 6, b = wid & 63;
  int k0 = b * 64;
  int tid = threadIdx.x;

  // stage Sp^T (vector copy from Xu)
  {
    int r = tid >> 2, c0 = (tid & 3) * 16;
    const U16* src = Xu + ((size_t)wid << 12) + r * 64 + c0;
    *(bf16x8*)&SP[r][c0]     = *(const bf16x8*)src;
    *(bf16x8*)&SP[r][c0 + 8] = *(const bf16x8*)(src + 8);
  }
  // stage VT (vector copy from VbT — already [e][k])
  {
    int r = tid >> 2, c0 = (tid & 3) * 16;
    const U16* src = VbT + ((size_t)wid << 12) + r * 64 + c0;
    *(bf16x8*)&VT[r][c0]     = *(const bf16x8*)src;
    *(bf16x8*)&VT[r][c0 + 8] = *(const bf16x8*)(src + 8);
  }

  int lane = tid & 63, wv = tid >> 6;
  int lr = lane & 15, lg = lane >> 4;
  int q0 = k0 + 16 * wv;

  // fused RoPE(Q) in-register (inline trig)
  bf16x8 Aq0, Aq1;
  {
    int t = q0 + lr;
    const float* qrow = Q + ((size_t)g * T + t) * DD;
    float x1[8], x2[8];
    *(float4*)&x1[0] = *(const float4*)(qrow + 8 * lg);
    *(float4*)&x1[4] = *(const float4*)(qrow + 8 * lg + 4);
    *(float4*)&x2[0] = *(const float4*)(qrow + 8 * lg + 32);
    *(float4*)&x2[4] = *(const float4*)(qrow + 8 * lg + 36);
#pragma unroll
    for (int i = 0; i < 8; ++i) {
      float invf = __expf(-(float)(8 * lg + i) * ROPE_C);
      float ang = (float)t * invf;
      float s, c;
      __sincosf(ang, &s, &c);
      Aq0[i] = (short)f2bf(x1[i] * c - x2[i] * s);
      Aq1[i] = (short)f2bf(x1[i] * s + x2[i] * c);
    }
  }
  __syncthreads();

  f32x4 O[4];
#pragma unroll
  for (int et = 0; et < 4; ++et) O[et] = (f32x4){0.f, 0.f, 0.f, 0.f};

  // term 1: Qr * Sp
#pragma unroll
  for (int et = 0; et < 4; ++et) {
    bf16x8 B0 = *(const bf16x8*)&SP[16 * et + lr][8 * lg];
    bf16x8 B1 = *(const bf16x8*)&SP[16 * et + lr][8 * lg + 32];
    O[et] = MFMA(Aq0, B0, O[et]);
    O[et] = MFMA(Aq1, B1, O[et]);
  }

  // term 2: diagonal block, strict lower mask; k-tiles kt<=wv only
  for (int kt = 0; kt <= wv; ++kt) {
    const U16* krow = Kr + ((size_t)g * T + k0 + 16 * kt + lr) * DD;
    bf16x8 Bk0 = *(const bf16x8*)(krow + 8 * lg);
    bf16x8 Bk1 = *(const bf16x8*)(krow + 8 * lg + 32);
    f32x4 s = {0.f, 0.f, 0.f, 0.f};
    s = MFMA(Aq0, Bk0, s);
    s = MFMA(Aq1, Bk1, s);
#pragma unroll
    for (int rr = 0; rr < 4; ++rr) {
      int qi = 16 * wv + 4 * lg + rr, ki = 16 * kt + lr;
      float val = (qi > ki) ? s[rr] : 0.f;
      SW[wv][4 * lg + rr][16 * kt + lr] = f2bf(val);
    }
  }
  for (int kt = wv + 1; kt < 4; ++kt) {
#pragma unroll
    for (int rr = 0; rr < 4; ++rr)
      SW[wv][4 * lg + rr][16 * kt + lr] = 0;
  }

  // A-fragments of masked S (same-wave LDS round trip)
  bf16x8 As0 = *(const bf16x8*)&SW[wv][lr][8 * lg];
  bf16x8 As1 = *(const bf16x8*)&SW[wv][lr][8 * lg + 32];

  // PV
#pragma unroll
  for (int et = 0; et < 4; ++et) {
    bf16x8 Bv0 = *(const bf16x8*)&VT[16 * et + lr][8 * lg];
    bf16x8 Bv1 = *(const bf16x8*)&VT[16 * et + lr][8 * lg + 32];
    O[et] = MFMA(As0, Bv0, O[et]);
    O[et] = MFMA(As1, Bv1, O[et]);
  }

  // store f32 output — non-temporal (terminal data)
#pragma unroll
  for (int et = 0; et < 4; ++et)
#pragma unroll
    for (int rr = 0; rr < 4; ++rr)
      __builtin_nontemporal_store(O[et][rr],
          &Out[((size_t)g * T + q0 + 4 * lg + rr) * DD + 16 * et + lr]);
}

extern "C" void kernel_launch(void* const* d_in, const int* in_sizes, int n_in,
                              void* d_out, int out_size, void* d_ws, size_t ws_size,
                              hipStream_t stream) {
  const float* Q = (const float*)d_in[0];
  const float* K = (const float*)d_in[1];
  const float* V = (const float*)d_in[2];
  float* Out = (float*)d_out;
  U16* W  = (U16*)d_ws;
  U16* Kr  = W;                              // 8.39 MB
  U16* VbT = W + 4194304;                    // 8.39 MB (per-block 64x64 [e][k])
  U16* Xu  = W + 8388608;                    // 8.39 MB
  unsigned* cnt = (unsigned*)(W + 12582912); // 64 B, self-correcting (no reset needed)
  k_phaseA<<<G * 64, 256, 0, stream>>>(K, V, Kr, VbT, Xu, cnt);
  k_phase3<<<G * 64, 256, 0, stream>>>(Q, Kr, VbT, Xu, Out);
}

// Round 11
// 34.592 us; speedup vs baseline: 3.5635x; 3.5635x over previous
//
#include <hip/hip_runtime.h>

#define G 16
#define T 4096
#define DD 64

typedef __attribute__((ext_vector_type(8))) short bf16x8;
typedef __attribute__((ext_vector_type(4))) short bf16x4;
typedef __attribute__((ext_vector_type(4))) float f32x4;
typedef unsigned short U16;

__device__ __forceinline__ float bf2f(U16 u) {
  union { unsigned int u; float f; } x; x.u = ((unsigned int)u) << 16; return x.f;
}
__device__ __forceinline__ U16 f2bf(float f) {
  union { float f; unsigned int u; } x; x.f = f;
  unsigned int r = x.u + 0x7FFFu + ((x.u >> 16) & 1u);
  return (U16)(r >> 16);
}

#define MFMA(a, b, c) __builtin_amdgcn_mfma_f32_16x16x32_bf16((a), (b), (c), 0, 0, 0)

// ln(10000)/32
#define ROPE_C 0.28782313662425575f

// ---------------- Phase 1: rope K -> Kr + KrT; V -> VT + VbT; X^T = Kr^T V -> Xu[e][d] ----------------
// Thread d-set {4qq+16m+c}: writer rows 4 apart -> 4-way LDS scatter conflict (was 8-way).
__global__ __launch_bounds__(256) void k_phase1(const float* __restrict__ K, const float* __restrict__ V,
                                                U16* __restrict__ Kr, U16* __restrict__ VbT,
                                                U16* __restrict__ Xu) {
  __shared__ __align__(16) U16 KrT[64][72];   // [d][k]
  __shared__ __align__(16) U16 VT[64][72];    // [e][k]
  int wid = blockIdx.x;            // g*64 + b
  int g = wid >> 6, b = wid & 63;
  int k0 = b * 64;
  int tid = threadIdx.x;

  int r = tid >> 2, qq = tid & 3;
  int t = k0 + r;
  size_t base = ((size_t)g * T + t) * DD;

  // K path: rope (inline trig) -> Kr global + KrT LDS (4-way scatter)
  {
    const float* rp = K + base;
    float x1[2][4], x2[2][4];
    *(float4*)x1[0] = *(const float4*)(rp + 4 * qq);
    *(float4*)x1[1] = *(const float4*)(rp + 4 * qq + 16);
    *(float4*)x2[0] = *(const float4*)(rp + 4 * qq + 32);
    *(float4*)x2[1] = *(const float4*)(rp + 4 * qq + 48);
#pragma unroll
    for (int m = 0; m < 2; ++m) {
      bf16x4 v1, v2;
#pragma unroll
      for (int c = 0; c < 4; ++c) {
        int d = 4 * qq + 16 * m + c;
        float invf = __expf(-(float)d * ROPE_C);
        float ang = (float)t * invf;
        float s, cc;
        __sincosf(ang, &s, &cc);
        float o1 = x1[m][c] * cc - x2[m][c] * s;
        float o2 = x1[m][c] * s + x2[m][c] * cc;
        U16 b1 = f2bf(o1), b2 = f2bf(o2);
        v1[c] = (short)b1; v2[c] = (short)b2;
        KrT[d][r]      = b1;
        KrT[d + 32][r] = b2;
      }
      *(bf16x4*)(Kr + base + 4 * qq + 16 * m)      = v1;
      *(bf16x4*)(Kr + base + 4 * qq + 16 * m + 32) = v2;
    }
  }
  // V path: f32 -> bf16 -> VT LDS (4-way scatter); VbT exported post-sync from LDS
  {
    const float* vp = V + base;
    float y1[2][4], y2[2][4];
    *(float4*)y1[0] = *(const float4*)(vp + 4 * qq);
    *(float4*)y1[1] = *(const float4*)(vp + 4 * qq + 16);
    *(float4*)y2[0] = *(const float4*)(vp + 4 * qq + 32);
    *(float4*)y2[1] = *(const float4*)(vp + 4 * qq + 48);
#pragma unroll
    for (int m = 0; m < 2; ++m) {
#pragma unroll
      for (int c = 0; c < 4; ++c) {
        int d = 4 * qq + 16 * m + c;
        VT[d][r]      = f2bf(y1[m][c]);
        VT[d + 32][r] = f2bf(y2[m][c]);
      }
    }
  }
  __syncthreads();

  // export V^T to global (vector LDS read -> dwordx4 stores)
  {
    int er = tid >> 2, cc = (tid & 3) * 16;
    *(bf16x8*)(VbT + ((size_t)wid << 12) + er * 64 + cc)     = *(const bf16x8*)&VT[er][cc];
    *(bf16x8*)(VbT + ((size_t)wid << 12) + er * 64 + cc + 8) = *(const bf16x8*)&VT[er][cc + 8];
  }

  int lane = tid & 63, wv = tid >> 6;
  int lr = lane & 15, lg = lane >> 4;

  // X^T = Kr^T * V (role-swapped layout, verified R8); b64 Xu stores
  {
    bf16x8 A0 = *(const bf16x8*)&KrT[16 * wv + lr][8 * lg];
    bf16x8 A1 = *(const bf16x8*)&KrT[16 * wv + lr][8 * lg + 32];
#pragma unroll
    for (int et = 0; et < 4; ++et) {
      bf16x8 B0 = *(const bf16x8*)&VT[16 * et + lr][8 * lg];
      bf16x8 B1 = *(const bf16x8*)&VT[16 * et + lr][8 * lg + 32];
      f32x4 acc = {0.f, 0.f, 0.f, 0.f};
      acc = MFMA(A0, B0, acc);
      acc = MFMA(A1, B1, acc);
      bf16x4 st;
#pragma unroll
      for (int rr = 0; rr < 4; ++rr) st[rr] = (short)f2bf(acc[rr]);
      *(bf16x4*)(Xu + ((size_t)wid << 12) + (16 * et + lr) * 64 + 16 * wv + 4 * lg) = st;
    }
  }
}

// ---------------- Phase 2: exclusive prefix over 64 block matrices per head ----------------
__global__ __launch_bounds__(256) void k_phase2c(U16* __restrict__ Xu) {
  int tau = blockIdx.x * 256 + threadIdx.x;   // 65536 threads = 16 heads * 4096 cols
  int hd = tau >> 12, col = tau & 4095;
  size_t base = ((size_t)hd << 18) + col;
  U16 v[64];
#pragma unroll
  for (int i = 0; i < 64; ++i)
    v[i] = Xu[base + ((size_t)i << 12)];
  float run = 0.f;
#pragma unroll
  for (int i = 0; i < 64; ++i) {
    float f = bf2f(v[i]);
    Xu[base + ((size_t)i << 12)] = f2bf(run);
    run += f;
  }
}

// ---------------- Phase 3: O_b = rope(Q)_b * Sp_b + tril_strict(rope(Q)_b Kr_b^T) V_b ----------------
// No shared staging, no __syncthreads: Sp/V B-fragments read directly from global (same-CU L2
// absorbs the 4x wave redundancy); only wave-private SW round-trip uses LDS.
__global__ __launch_bounds__(256) void k_phase3(const float* __restrict__ Q, const U16* __restrict__ Kr,
                                                const U16* __restrict__ VbT, const U16* __restrict__ Xu,
                                                float* __restrict__ Out) {
  __shared__ __align__(16) U16 SW[4][16][72];  // per-wave masked S round-trip
  int wid = blockIdx.x;
  int g = wid >> 6, b = wid & 63;
  int k0 = b * 64;
  int tid = threadIdx.x;

  int lane = tid & 63, wv = tid >> 6;
  int lr = lane & 15, lg = lane >> 4;
  int q0 = k0 + 16 * wv;

  const U16* xb = Xu  + ((size_t)wid << 12);
  const U16* vb = VbT + ((size_t)wid << 12);

  // fused RoPE(Q) in-register (inline trig)
  bf16x8 Aq0, Aq1;
  {
    int t = q0 + lr;
    const float* qrow = Q + ((size_t)g * T + t) * DD;
    float x1[8], x2[8];
    *(float4*)&x1[0] = *(const float4*)(qrow + 8 * lg);
    *(float4*)&x1[4] = *(const float4*)(qrow + 8 * lg + 4);
    *(float4*)&x2[0] = *(const float4*)(qrow + 8 * lg + 32);
    *(float4*)&x2[4] = *(const float4*)(qrow + 8 * lg + 36);
#pragma unroll
    for (int i = 0; i < 8; ++i) {
      float invf = __expf(-(float)(8 * lg + i) * ROPE_C);
      float ang = (float)t * invf;
      float s, c;
      __sincosf(ang, &s, &c);
      Aq0[i] = (short)f2bf(x1[i] * c - x2[i] * s);
      Aq1[i] = (short)f2bf(x1[i] * s + x2[i] * c);
    }
  }

  f32x4 O[4];
#pragma unroll
  for (int et = 0; et < 4; ++et) O[et] = (f32x4){0.f, 0.f, 0.f, 0.f};

  // term 1: Qr * Sp — B-fragments straight from Xu (global, L2-warm)
#pragma unroll
  for (int et = 0; et < 4; ++et) {
    bf16x8 B0 = *(const bf16x8*)(xb + (16 * et + lr) * 64 + 8 * lg);
    bf16x8 B1 = *(const bf16x8*)(xb + (16 * et + lr) * 64 + 8 * lg + 32);
    O[et] = MFMA(Aq0, B0, O[et]);
    O[et] = MFMA(Aq1, B1, O[et]);
  }

  // term 2: diagonal block, strict lower mask; k-tiles kt<=wv only
  for (int kt = 0; kt <= wv; ++kt) {
    const U16* krow = Kr + ((size_t)g * T + k0 + 16 * kt + lr) * DD;
    bf16x8 Bk0 = *(const bf16x8*)(krow + 8 * lg);
    bf16x8 Bk1 = *(const bf16x8*)(krow + 8 * lg + 32);
    f32x4 s = {0.f, 0.f, 0.f, 0.f};
    s = MFMA(Aq0, Bk0, s);
    s = MFMA(Aq1, Bk1, s);
#pragma unroll
    for (int rr = 0; rr < 4; ++rr) {
      int qi = 16 * wv + 4 * lg + rr, ki = 16 * kt + lr;
      float val = (qi > ki) ? s[rr] : 0.f;
      SW[wv][4 * lg + rr][16 * kt + lr] = f2bf(val);
    }
  }
  for (int kt = wv + 1; kt < 4; ++kt) {
#pragma unroll
    for (int rr = 0; rr < 4; ++rr)
      SW[wv][4 * lg + rr][16 * kt + lr] = 0;
  }

  // A-fragments of masked S (same-wave LDS round trip; in-order per wave, no barrier needed)
  bf16x8 As0 = *(const bf16x8*)&SW[wv][lr][8 * lg];
  bf16x8 As1 = *(const bf16x8*)&SW[wv][lr][8 * lg + 32];

  // PV — B-fragments straight from VbT (global, L2-warm)
#pragma unroll
  for (int et = 0; et < 4; ++et) {
    bf16x8 Bv0 = *(const bf16x8*)(vb + (16 * et + lr) * 64 + 8 * lg);
    bf16x8 Bv1 = *(const bf16x8*)(vb + (16 * et + lr) * 64 + 8 * lg + 32);
    O[et] = MFMA(As0, Bv0, O[et]);
    O[et] = MFMA(As1, Bv1, O[et]);
  }

  // store f32 output — non-temporal (terminal data)
#pragma unroll
  for (int et = 0; et < 4; ++et)
#pragma unroll
    for (int rr = 0; rr < 4; ++rr)
      __builtin_nontemporal_store(O[et][rr],
          &Out[((size_t)g * T + q0 + 4 * lg + rr) * DD + 16 * et + lr]);
}

extern "C" void kernel_launch(void* const* d_in, const int* in_sizes, int n_in,
                              void* d_out, int out_size, void* d_ws, size_t ws_size,
                              hipStream_t stream) {
  const float* Q = (const float*)d_in[0];
  const float* K = (const float*)d_in[1];
  const float* V = (const float*)d_in[2];
  float* Out = (float*)d_out;
  U16* W  = (U16*)d_ws;
  U16* Kr  = W;                 // 8.39 MB
  U16* VbT = W + 4194304;       // 8.39 MB (per-block 64x64 [e][k])
  U16* Xu  = W + 8388608;       // 8.39 MB   (24 MiB of ws)
  k_phase1<<<G * 64, 256, 0, stream>>>(K, V, Kr, VbT, Xu);
  k_phase2c<<<256, 256, 0, stream>>>(Xu);
  k_phase3<<<G * 64, 256, 0, stream>>>(Q, Kr, VbT, Xu, Out);
}

// Round 12
// 30.118 us; speedup vs baseline: 4.0929x; 1.1486x over previous
//
#include <hip/hip_runtime.h>

#define G 16
#define T 4096
#define DD 64

typedef __attribute__((ext_vector_type(8))) short bf16x8;
typedef __attribute__((ext_vector_type(4))) short bf16x4;
typedef __attribute__((ext_vector_type(4))) float f32x4;
typedef unsigned short U16;

__device__ __forceinline__ float bf2f(U16 u) {
  union { unsigned int u; float f; } x; x.u = ((unsigned int)u) << 16; return x.f;
}
__device__ __forceinline__ U16 f2bf(float f) {
  union { float f; unsigned int u; } x; x.f = f;
  unsigned int r = x.u + 0x7FFFu + ((x.u >> 16) & 1u);
  return (U16)(r >> 16);
}

#define MFMA(a, b, c) __builtin_amdgcn_mfma_f32_16x16x32_bf16((a), (b), (c), 0, 0, 0)

// ln(10000)/32
#define ROPE_C 0.28782313662425575f

// ---------------- Phase 1 (BLOCK=128): rope K -> Kr + KrT[64][128]; V -> VT + VbT[e][128];
//                  X_j = Kr_j^T V_j (k=128, f32 accum) -> Xu[e][d] ----------------
__global__ __launch_bounds__(256) void k_phase1(const float* __restrict__ K, const float* __restrict__ V,
                                                U16* __restrict__ Kr, U16* __restrict__ VbT,
                                                U16* __restrict__ Xu) {
  __shared__ __align__(16) U16 KrT[64][136];   // [d][k=128]
  __shared__ __align__(16) U16 VT[64][136];    // [e][k=128]
  int wid = blockIdx.x;            // g*32 + j
  int g = wid >> 5, j = wid & 31;
  int k0 = j * 128;
  int tid = threadIdx.x;
  int r = tid >> 2, qq = tid & 3, d0 = qq * 8;

#pragma unroll
  for (int h = 0; h < 2; ++h) {
    int t = k0 + 64 * h + r;
    size_t base = ((size_t)g * T + t) * DD;
    // K path: rope (inline trig) -> Kr global + KrT LDS (transposed scatter, R6 pattern)
    {
      const float* rp = K + base;
      float x1[8], x2[8];
      *(float4*)&x1[0] = *(const float4*)(rp + d0);
      *(float4*)&x1[4] = *(const float4*)(rp + d0 + 4);
      *(float4*)&x2[0] = *(const float4*)(rp + d0 + 32);
      *(float4*)&x2[4] = *(const float4*)(rp + d0 + 36);
      bf16x8 v1, v2;
#pragma unroll
      for (int i = 0; i < 8; ++i) {
        float invf = __expf(-(float)(d0 + i) * ROPE_C);
        float ang = (float)t * invf;
        float s, c;
        __sincosf(ang, &s, &c);
        float o1 = x1[i] * c - x2[i] * s;
        float o2 = x1[i] * s + x2[i] * c;
        U16 b1 = f2bf(o1), b2 = f2bf(o2);
        v1[i] = (short)b1; v2[i] = (short)b2;
        KrT[d0 + i][64 * h + r]      = b1;
        KrT[d0 + i + 32][64 * h + r] = b2;
      }
      *(bf16x8*)(Kr + base + d0)      = v1;
      *(bf16x8*)(Kr + base + d0 + 32) = v2;
    }
    // V path: f32 -> bf16 -> VT LDS (transposed scatter)
    {
      const float* vp = V + base;
      float y1[8], y2[8];
      *(float4*)&y1[0] = *(const float4*)(vp + d0);
      *(float4*)&y1[4] = *(const float4*)(vp + d0 + 4);
      *(float4*)&y2[0] = *(const float4*)(vp + d0 + 32);
      *(float4*)&y2[4] = *(const float4*)(vp + d0 + 36);
#pragma unroll
      for (int i = 0; i < 8; ++i) {
        VT[d0 + i][64 * h + r]      = f2bf(y1[i]);
        VT[d0 + i + 32][64 * h + r] = f2bf(y2[i]);
      }
    }
  }
  __syncthreads();

  // export V^T [e][128] to global (vector LDS read -> dwordx4 stores)
  {
    int er = tid >> 2, cc = (tid & 3) * 32;
    U16* dst = VbT + ((size_t)wid << 13) + er * 128 + cc;
    *(bf16x8*)(dst)      = *(const bf16x8*)&VT[er][cc];
    *(bf16x8*)(dst + 8)  = *(const bf16x8*)&VT[er][cc + 8];
    *(bf16x8*)(dst + 16) = *(const bf16x8*)&VT[er][cc + 16];
    *(bf16x8*)(dst + 24) = *(const bf16x8*)&VT[er][cc + 24];
  }

  int lane = tid & 63, wv = tid >> 6;
  int lr = lane & 15, lg = lane >> 4;

  // X = Kr^T V over k=128: accumulate 4 MFMA in f32, single bf16 round (more accurate than R6)
  {
    bf16x8 A[2][2];
#pragma unroll
    for (int h = 0; h < 2; ++h) {
      A[h][0] = *(const bf16x8*)&KrT[16 * wv + lr][64 * h + 8 * lg];
      A[h][1] = *(const bf16x8*)&KrT[16 * wv + lr][64 * h + 8 * lg + 32];
    }
#pragma unroll
    for (int et = 0; et < 4; ++et) {
      f32x4 acc = {0.f, 0.f, 0.f, 0.f};
#pragma unroll
      for (int h = 0; h < 2; ++h) {
        bf16x8 B0 = *(const bf16x8*)&VT[16 * et + lr][64 * h + 8 * lg];
        bf16x8 B1 = *(const bf16x8*)&VT[16 * et + lr][64 * h + 8 * lg + 32];
        acc = MFMA(A[h][0], B0, acc);
        acc = MFMA(A[h][1], B1, acc);
      }
      bf16x4 st;
#pragma unroll
      for (int rr = 0; rr < 4; ++rr) st[rr] = (short)f2bf(acc[rr]);
      *(bf16x4*)(Xu + ((size_t)wid << 12) + (16 * et + lr) * 64 + 16 * wv + 4 * lg) = st;
    }
  }
}

// ---------------- Phase 2: exclusive prefix over 32 block matrices per head ----------------
__global__ __launch_bounds__(256) void k_phase2c(U16* __restrict__ Xu) {
  int tau = blockIdx.x * 256 + threadIdx.x;   // 65536 threads = 16 heads * 4096 cols
  int hd = tau >> 12, col = tau & 4095;
  size_t base = ((size_t)hd << 17) + col;     // 32 blocks * 4096
  U16 v[32];
#pragma unroll
  for (int i = 0; i < 32; ++i)
    v[i] = Xu[base + ((size_t)i << 12)];
  float run = 0.f;
#pragma unroll
  for (int i = 0; i < 32; ++i) {
    float f = bf2f(v[i]);
    Xu[base + ((size_t)i << 12)] = f2bf(run);
    run += f;
  }
}

// ---------------- Phase 3 (BLOCK=128): O = rope(Q) Sp + tril_strict(rope(Q) Kr^T) V ----------------
__global__ __launch_bounds__(256) void k_phase3(const float* __restrict__ Q, const U16* __restrict__ Kr,
                                                const U16* __restrict__ VbT, const U16* __restrict__ Xu,
                                                float* __restrict__ Out) {
  __shared__ __align__(16) U16 SP[64][72];      // Sp^T [e][d]
  __shared__ __align__(16) U16 VT[64][136];     // [e][k=128]
  __shared__ __align__(16) U16 SW[4][16][136];  // per-wave masked S row [16 q][128 k]
  int wid = blockIdx.x;            // g*32 + j
  int g = wid >> 5, j = wid & 31;
  int k0 = j * 128;
  int tid = threadIdx.x;

  // stage Sp^T (vector copy from Xu)
  {
    int r = tid >> 2, c0 = (tid & 3) * 16;
    const U16* src = Xu + ((size_t)wid << 12) + r * 64 + c0;
    *(bf16x8*)&SP[r][c0]     = *(const bf16x8*)src;
    *(bf16x8*)&SP[r][c0 + 8] = *(const bf16x8*)(src + 8);
  }
  // stage VT (vector copy from VbT — already [e][128])
  {
    int r = tid >> 2, cc = (tid & 3) * 32;
    const U16* src = VbT + ((size_t)wid << 13) + r * 128 + cc;
    *(bf16x8*)&VT[r][cc]      = *(const bf16x8*)src;
    *(bf16x8*)&VT[r][cc + 8]  = *(const bf16x8*)(src + 8);
    *(bf16x8*)&VT[r][cc + 16] = *(const bf16x8*)(src + 16);
    *(bf16x8*)&VT[r][cc + 24] = *(const bf16x8*)(src + 24);
  }
  __syncthreads();

  int lane = tid & 63, wv = tid >> 6;
  int lr = lane & 15, lg = lane >> 4;

  f32x4 O[2][4];
#pragma unroll
  for (int h = 0; h < 2; ++h)
#pragma unroll
    for (int et = 0; et < 4; ++et) O[h][et] = (f32x4){0.f, 0.f, 0.f, 0.f};

#pragma unroll
  for (int h = 0; h < 2; ++h) {
    int q0 = k0 + 64 * h + 16 * wv;
    // fused RoPE(Q) in-register
    bf16x8 Aq0, Aq1;
    {
      int t = q0 + lr;
      const float* qrow = Q + ((size_t)g * T + t) * DD;
      float x1[8], x2[8];
      *(float4*)&x1[0] = *(const float4*)(qrow + 8 * lg);
      *(float4*)&x1[4] = *(const float4*)(qrow + 8 * lg + 4);
      *(float4*)&x2[0] = *(const float4*)(qrow + 8 * lg + 32);
      *(float4*)&x2[4] = *(const float4*)(qrow + 8 * lg + 36);
#pragma unroll
      for (int i = 0; i < 8; ++i) {
        float invf = __expf(-(float)(8 * lg + i) * ROPE_C);
        float ang = (float)t * invf;
        float s, c;
        __sincosf(ang, &s, &c);
        Aq0[i] = (short)f2bf(x1[i] * c - x2[i] * s);
        Aq1[i] = (short)f2bf(x1[i] * s + x2[i] * c);
      }
    }

    // term 1: Qr * Sp
#pragma unroll
    for (int et = 0; et < 4; ++et) {
      bf16x8 B0 = *(const bf16x8*)&SP[16 * et + lr][8 * lg];
      bf16x8 B1 = *(const bf16x8*)&SP[16 * et + lr][8 * lg + 32];
      O[h][et] = MFMA(Aq0, B0, O[h][et]);
      O[h][et] = MFMA(Aq1, B1, O[h][et]);
    }

    // zero this wave's SW row-block (in-order per wave; overwritten below where computed)
    {
      bf16x8 z = {0, 0, 0, 0, 0, 0, 0, 0};
      *(bf16x8*)&SW[wv][lr][32 * lg]      = z;
      *(bf16x8*)&SW[wv][lr][32 * lg + 8]  = z;
      *(bf16x8*)&SW[wv][lr][32 * lg + 16] = z;
      *(bf16x8*)&SW[wv][lr][32 * lg + 24] = z;
    }

    // h==1: full (unmasked) tiles over sub-block 0 keys
    if (h == 1) {
#pragma unroll
      for (int kt0 = 0; kt0 < 4; ++kt0) {
        const U16* krow = Kr + ((size_t)g * T + k0 + 16 * kt0 + lr) * DD;
        bf16x8 Bk0 = *(const bf16x8*)(krow + 8 * lg);
        bf16x8 Bk1 = *(const bf16x8*)(krow + 8 * lg + 32);
        f32x4 s = {0.f, 0.f, 0.f, 0.f};
        s = MFMA(Aq0, Bk0, s);
        s = MFMA(Aq1, Bk1, s);
        bf16x4 st;
#pragma unroll
        for (int rr = 0; rr < 4; ++rr) st[rr] = (short)f2bf(s[rr]);
        // store scalar (non-contiguous in k): 4 u16 writes
#pragma unroll
        for (int rr = 0; rr < 4; ++rr)
          SW[wv][4 * lg + rr][16 * kt0 + lr] = (U16)st[rr];
      }
    }

    // masked diagonal tiles within sub-block h: kt <= wv
    for (int kt = 0; kt <= wv; ++kt) {
      const U16* krow = Kr + ((size_t)g * T + k0 + 64 * h + 16 * kt + lr) * DD;
      bf16x8 Bk0 = *(const bf16x8*)(krow + 8 * lg);
      bf16x8 Bk1 = *(const bf16x8*)(krow + 8 * lg + 32);
      f32x4 s = {0.f, 0.f, 0.f, 0.f};
      s = MFMA(Aq0, Bk0, s);
      s = MFMA(Aq1, Bk1, s);
#pragma unroll
      for (int rr = 0; rr < 4; ++rr) {
        int qi = 16 * wv + 4 * lg + rr, ki = 16 * kt + lr;   // local within sub-block
        float val = (qi > ki) ? s[rr] : 0.f;
        SW[wv][4 * lg + rr][64 * h + 16 * kt + lr] = f2bf(val);
      }
    }

    // PV: A-frags from SW (same-wave round trip), B-frags from VT; k-slices active for this h
    int nks = (h == 0) ? 2 : 4;
    for (int ks = 0; ks < nks; ++ks) {
      bf16x8 As = *(const bf16x8*)&SW[wv][lr][32 * ks + 8 * lg];
#pragma unroll
      for (int et = 0; et < 4; ++et) {
        bf16x8 Bv = *(const bf16x8*)&VT[16 * et + lr][32 * ks + 8 * lg];
        O[h][et] = MFMA(As, Bv, O[h][et]);
      }
    }
  }

  // store f32 output — non-temporal (terminal data)
#pragma unroll
  for (int h = 0; h < 2; ++h) {
    int q0 = k0 + 64 * h + 16 * wv;
#pragma unroll
    for (int et = 0; et < 4; ++et)
#pragma unroll
      for (int rr = 0; rr < 4; ++rr)
        __builtin_nontemporal_store(O[h][et][rr],
            &Out[((size_t)g * T + q0 + 4 * lg + rr) * DD + 16 * et + lr]);
  }
}

extern "C" void kernel_launch(void* const* d_in, const int* in_sizes, int n_in,
                              void* d_out, int out_size, void* d_ws, size_t ws_size,
                              hipStream_t stream) {
  const float* Q = (const float*)d_in[0];
  const float* K = (const float*)d_in[1];
  const float* V = (const float*)d_in[2];
  float* Out = (float*)d_out;
  U16* W  = (U16*)d_ws;
  U16* Kr  = W;                 // 8.39 MB
  U16* VbT = W + 4194304;       // 8.39 MB (per 128-block 64x128 [e][k])
  U16* Xu  = W + 8388608;       // 4.19 MB (512 blocks x 64x64)
  k_phase1<<<G * 32, 256, 0, stream>>>(K, V, Kr, VbT, Xu);
  k_phase2c<<<256, 256, 0, stream>>>(Xu);
  k_phase3<<<G * 32, 256, 0, stream>>>(Q, Kr, VbT, Xu, Out);
}